// Round 10
// baseline (294.232 us; speedup 1.0000x reference)
//
#include <hip/hip_runtime.h>
#include <stdint.h>

// RNN scan: h_t = tanh(h_{t-1} @ Whh + b_hh + x_t * Wxh + b_xh), out = h_T @ Wout + b_out
// B=16384 rows, T=1024 steps, H=32 hidden.
//
// Round 11: j-split each tile across 2 waves -> 2 waves/SIMD (was structurally 1).
// r9 model (validated 3 rounds): 483 cyc/step = 343 busy + ~140 STALL; the stall
// is MFMA/trans latency on the serial chain with nothing co-resident to fill it.
// 1024 tiles = 1024 waves = SIMD count, so occupancy can only rise by splitting
// the step: wave w computes j-half w (1 MFMA, 4 tanh = 8 trans, half the busy),
// halves exchange h via a double-buffered LDS slab with ONE __syncthreads per
// step. Per-SIMD issue is conserved (~380 cyc/step); the sibling wave fills the
// chain bubbles. The permlane permutation machinery is now unnecessary (LDS
// routes arbitrarily) -> identity j-map, re-derived end to end.
//
// LDS layout: hx[buf][row][20] u32 words; word p = h-pair (h[2p],h[2p+1]).
// write: wave w lane(r,G) -> words 8w+2G..+1 (ds_write_b64, bank-floor).
// read:  lane(r,G) -> words 4G..4G+3 (ds_read_b128, 16B-aligned, bank-floor:
//        stride 20 -> 8 lanes/residue x 1 word/bank = inherent b128 minimum).
// step t reads buf[t%2], writes buf[(t+1)%2]; barrier at step end orders both
// the RAW (write t -> read t+1) and WAR (read t -> write t+1) pairs.
//
// Arithmetic per h is operation-identical to round 9 -> absmax should reproduce
// 0.00390625 exactly (built-in routing check).
//
// MFMA 16x16x32 f16 layouts (m89-verified):
//   A: lane l: m = l&15, k = 8*(l>>4)+e    B: lane l: n = l&15, k = 8*(l>>4)+e
//   D: lane l: n = l&15, m = 4*(l>>4)+reg

typedef _Float16 half8  __attribute__((ext_vector_type(8)));
typedef float    f32x4  __attribute__((ext_vector_type(4)));
typedef uint32_t u32x4  __attribute__((ext_vector_type(4)));

constexpr int Tlen   = 1024;
constexpr int NTILES = 16384 / 16;            // 1024 blocks x 128 thr (2 waves)

constexpr float KSC = 2.8853900817779268f;    // +2*log2(e)

// r = 1/(1 + 2^argP);  tanh(s) = fma(-2, r, 1).
// argP>=128: exp2=inf -> rcp=0 -> 1.  argP<=-127: exp2=0 -> rcp(1)=1 -> -1. Safe.
__device__ __forceinline__ float sig_r(float argP) {
    float e = __builtin_amdgcn_exp2f(argP);
    return __builtin_amdgcn_rcpf(1.0f + e);
}

// w = { f16_rtn(-2*rLo+1), f16_rtn(-2*rHi+1) } via v_fma_mixlo/hi_f16 (1 op each).
__device__ __forceinline__ uint32_t tanh_pack_pair(float rLo, float rHi,
                                                   float cm2, float c1) {
    uint32_t w;
    asm("v_fma_mixlo_f16 %0, %1, %2, %3" : "=v"(w) : "v"(rLo), "v"(cm2), "v"(c1));
    asm("v_fma_mixhi_f16 %0, %1, %2, %3" : "+v"(w) : "v"(rHi), "v"(cm2), "v"(c1));
    return w;
}

__global__ __launch_bounds__(128, 1)
void rnn_scan_mfma(const float* __restrict__ x,    // [B,T]
                   const float* __restrict__ Wxh,  // [1,H]
                   const float* __restrict__ b_xh, // [H]
                   const float* __restrict__ Whh,  // [H,H] row-major (i,j)
                   const float* __restrict__ b_hh, // [H]
                   const float* __restrict__ Wout, // [H,1]
                   const float* __restrict__ b_out,// [1]
                   float* __restrict__ out)        // [B,1]
{
    __shared__ uint32_t hx[2][16][20];   // 2.5 KB double-buffered h exchange
    __shared__ float    vred[2][16];     // epilogue cross-wave partials

    const int tid  = threadIdx.x;
    const int wv   = tid >> 6;           // wave = j-half (0: j<16, 1: j>=16)
    const int lane = tid & 63;
    const int r16  = lane & 15;
    const int G    = lane >> 4;          // 0..3
    const int tile = blockIdx.x;

    // A fragment: this wave's 16 W-columns. A[m=l&15 -> j=16wv+m][k=8G+e].
    half8 W1;
    #pragma unroll
    for (int e = 0; e < 8; ++e)
        W1[e] = (_Float16)(KSC * Whh[(8 * G + e) * 32 + 16 * wv + r16]);

    // D reg q -> j = 16wv + 4G + q
    float wx[4], bb[4], wo[4];
    #pragma unroll
    for (int q = 0; q < 4; ++q) {
        int j = 16 * wv + 4 * G + q;
        wx[q] = KSC * Wxh[j];
        bb[q] = KSC * (b_hh[j] + b_xh[j]);
        wo[q] = Wout[j];
    }
    const float bout = b_out[0];
    const float cm2 = -2.0f, c1 = 1.0f;

    // precomputed LDS addresses (loop-invariant)
    uint32_t* rdp[2] = { &hx[0][r16][4 * G],          &hx[1][r16][4 * G] };
    uint32_t* wrp[2] = { &hx[0][r16][8 * wv + 2 * G], &hx[1][r16][8 * wv + 2 * G] };

    // h0 = 0: each wave zeroes its own write-slots in buf0
    *(uint2*)wrp[0] = make_uint2(0u, 0u);
    __syncthreads();

    const float* xrow = x + (size_t)(tile * 16 + r16) * Tlen;
    float r0 = 0.5f, r1 = 0.5f, r2 = 0.5f, r3 = 0.5f;   // r=0.5 <=> t=0

    auto step = [&](float xv, const int p) {            // p = read-buffer parity
        f32x4 c;
        #pragma unroll
        for (int q = 0; q < 4; ++q) c[q] = __builtin_fmaf(xv, wx[q], bb[q]);

        u32x4 u  = *(const u32x4*)rdp[p];               // ds_read_b128 (full h)
        half8 hb = __builtin_bit_cast(half8, u);

        f32x4 a = __builtin_amdgcn_mfma_f32_16x16x32_f16(W1, hb, c, 0, 0, 0);

        r0 = sig_r(a[0]);
        r1 = sig_r(a[1]);
        r2 = sig_r(a[2]);
        r3 = sig_r(a[3]);

        uint32_t wA = tanh_pack_pair(r0, r1, cm2, c1);
        uint32_t wB = tanh_pack_pair(r2, r3, cm2, c1);
        *(uint2*)wrp[p ^ 1] = make_uint2(wA, wB);       // ds_write_b64 (own half)
        __syncthreads();
    };

    // x in registers: 8 steps per iteration (2 x float4), prefetched one iter ahead.
    float4 xa = *(const float4*)&xrow[0];
    float4 xb = *(const float4*)&xrow[4];
    #pragma unroll 1
    for (int t8 = 0; t8 < Tlen / 8 - 1; ++t8) {
        float4 na = *(const float4*)&xrow[8 * t8 +  8];
        float4 nb = *(const float4*)&xrow[8 * t8 + 12];
        step(xa.x, 0); step(xa.y, 1); step(xa.z, 0); step(xa.w, 1);
        step(xb.x, 0); step(xb.y, 1); step(xb.z, 0); step(xb.w, 1);
        xa = na; xb = nb;
    }
    step(xa.x, 0); step(xa.y, 1); step(xa.z, 0); step(xa.w, 1);
    step(xb.x, 0); step(xb.y, 1); step(xb.z, 0); step(xb.w, 1);

    // epilogue: t = fma(-2,r,1); partial over this wave's 4 j, reduce over G,
    // then combine the two waves' halves via LDS.
    float t0 = __builtin_fmaf(cm2, r0, c1), t1 = __builtin_fmaf(cm2, r1, c1);
    float t2 = __builtin_fmaf(cm2, r2, c1), t3 = __builtin_fmaf(cm2, r3, c1);
    float v = t0 * wo[0] + t1 * wo[1] + t2 * wo[2] + t3 * wo[3];
    v += __shfl_xor(v, 16, 64);
    v += __shfl_xor(v, 32, 64);
    if (lane < 16) vred[wv][r16] = v;
    __syncthreads();
    if (wv == 0 && lane < 16)
        out[tile * 16 + r16] = vred[0][r16] + vred[1][r16] + bout;
}

extern "C" void kernel_launch(void* const* d_in, const int* in_sizes, int n_in,
                              void* d_out, int out_size, void* d_ws, size_t ws_size,
                              hipStream_t stream) {
    const float* x     = (const float*)d_in[0];
    const float* Wxh   = (const float*)d_in[1];
    const float* b_xh  = (const float*)d_in[2];
    const float* Whh   = (const float*)d_in[3];
    const float* b_hh  = (const float*)d_in[4];
    const float* Wout  = (const float*)d_in[5];
    const float* b_out = (const float*)d_in[6];
    float* outp = (float*)d_out;

    rnn_scan_mfma<<<NTILES, 128, 0, stream>>>(x, Wxh, b_xh, Whh, b_hh, Wout,
                                              b_out, outp);
}